// Round 7
// baseline (247.485 us; speedup 1.0000x reference)
//
#include <hip/hip_runtime.h>
#include <hip/hip_bf16.h>

#define BDIM 8
#define LDIM 128
#define TDIM 64
#define NFEAT 1024
#define HNUM 16
#define DH 64

#define GM 4096  // rows of pooled = B*T*B
#define GN 1024
#define GK 1024

typedef __attribute__((ext_vector_type(8))) short short8;
typedef __attribute__((ext_vector_type(4))) float f32x4;

// round-to-nearest-even f32 -> bf16 bits
__device__ __forceinline__ unsigned short f2bf(float x) {
  union { float f; unsigned u; } v; v.f = x;
  unsigned r = v.u + 0x7fffu + ((v.u >> 16) & 1u);
  return (unsigned short)(r >> 16);
}

__device__ __forceinline__ void gload_lds16(const void* g, void* l) {
  __builtin_amdgcn_global_load_lds((const __attribute__((address_space(1))) void*)g,
                                   (__attribute__((address_space(3))) void*)l, 16, 0, 0);
}

// ---------------------------------------------------------------------------
// Kernel 1: mean (row bl) + weff (row f=bl).  1024 blocks x 256 = 16 waves/CU.
// (R6-proven body, verbatim.)
// ---------------------------------------------------------------------------
__global__ __launch_bounds__(256) void mean_weff_kernel(
    const float* __restrict__ kv, const float* __restrict__ Wo,
    const float* __restrict__ Wv, const float* __restrict__ bv,
    const float* __restrict__ bo, float* __restrict__ km,
    unsigned short* __restrict__ Weff, float* __restrict__ beff) {
  __shared__ float worow[NFEAT];
  __shared__ float red[256];
  const int bl = blockIdx.x;
  const int tid = threadIdx.x;
  // ---- mean over t of kv[bl, t, :] ----
  {
    const float* src = kv + (size_t)bl * (TDIM * NFEAT) + tid * 4;
    float4 acc = make_float4(0.f, 0.f, 0.f, 0.f);
    for (int t0 = 0; t0 < TDIM; t0 += 8) {
      float4 v[8];
#pragma unroll
      for (int jj = 0; jj < 8; ++jj)
        v[jj] = *(const float4*)(src + (t0 + jj) * NFEAT);
#pragma unroll
      for (int jj = 0; jj < 8; ++jj) {
        acc.x += v[jj].x; acc.y += v[jj].y; acc.z += v[jj].z; acc.w += v[jj].w;
      }
    }
    const float s = 1.f / TDIM;
    const float4 o = make_float4(acc.x * s, acc.y * s, acc.z * s, acc.w * s);
    *(float4*)(km + (size_t)bl * NFEAT + tid * 4) = o;
  }
  // ---- weff row f = bl ----
  {
    const int f = bl;
    *(float4*)(worow + tid * 4) = *(const float4*)(Wo + (size_t)f * NFEAT + tid * 4);
    __syncthreads();
    const int g0 = tid * 4;
    const int hbase = (g0 >> 6) << 6;
    const int i0 = g0 & 63;
    float a0 = 0, a1 = 0, a2 = 0, a3 = 0;
#pragma unroll 4
    for (int d = 0; d < DH; ++d) {
      const float wod = worow[hbase + d];
      const float4 wv4 = *(const float4*)(Wv + d * DH + i0);
      a0 += wod * wv4.x; a1 += wod * wv4.y; a2 += wod * wv4.z; a3 += wod * wv4.w;
    }
    ushort4 pk;
    pk.x = f2bf(a0); pk.y = f2bf(a1); pk.z = f2bf(a2); pk.w = f2bf(a3);
    *(ushort4*)(Weff + (size_t)f * NFEAT + g0) = pk;
    red[tid] = worow[g0 + 0] * bv[i0 + 0] + worow[g0 + 1] * bv[i0 + 1] +
               worow[g0 + 2] * bv[i0 + 2] + worow[g0 + 3] * bv[i0 + 3];
    __syncthreads();
    for (int sft = 128; sft > 0; sft >>= 1) {
      if (tid < sft) red[tid] += red[tid + sft];
      __syncthreads();
    }
    if (tid == 0) beff[f] = bo[f] + red[0];
  }
}

// ---------------------------------------------------------------------------
// Kernel 2: attn (R6-proven body, verbatim).  PROBE: launched 9x this round.
// ---------------------------------------------------------------------------
__global__ __launch_bounds__(128) void attn_kernel(const float* __restrict__ q,
                                                   const float* __restrict__ km,
                                                   const float* __restrict__ Wq,
                                                   const float* __restrict__ bq,
                                                   const float* __restrict__ Wk,
                                                   float* __restrict__ attn) {
  __shared__ float qp_s[BDIM * DH];
  __shared__ float qk_s[BDIM * DH];
  __shared__ float sw[BDIM * LDIM];
  __shared__ float mred[BDIM], ired[BDIM];
  const int b1 = blockIdx.x;
  const int h  = blockIdx.y;
  const int tid = threadIdx.x;

  {
    const int e0 = tid * 4;
    const int b2 = e0 >> 6;
    const int d0 = e0 & 63;
    float a0 = bq[d0], a1 = bq[d0 + 1], a2 = bq[d0 + 2], a3 = bq[d0 + 3];
    const float* qrow = q + b2 * NFEAT + h * DH;
#pragma unroll 4
    for (int i = 0; i < DH; ++i) {
      const float qv = qrow[i];
      a0 += qv * Wq[(d0 + 0) * DH + i];
      a1 += qv * Wq[(d0 + 1) * DH + i];
      a2 += qv * Wq[(d0 + 2) * DH + i];
      a3 += qv * Wq[(d0 + 3) * DH + i];
    }
    qp_s[e0 + 0] = a0; qp_s[e0 + 1] = a1; qp_s[e0 + 2] = a2; qp_s[e0 + 3] = a3;
  }
  __syncthreads();
  {
    const int e0 = tid * 4;
    const int b2 = e0 >> 6;
    const int i0 = e0 & 63;
    float a0 = 0, a1 = 0, a2 = 0, a3 = 0;
#pragma unroll 4
    for (int d = 0; d < DH; ++d) {
      const float qpv = qp_s[b2 * DH + d];
      const float4 wk4 = *(const float4*)(Wk + d * DH + i0);
      a0 += qpv * wk4.x; a1 += qpv * wk4.y; a2 += qpv * wk4.z; a3 += qpv * wk4.w;
    }
    qk_s[e0 + 0] = a0; qk_s[e0 + 1] = a1; qk_s[e0 + 2] = a2; qk_s[e0 + 3] = a3;
  }
  __syncthreads();
  {
    const float* kmrow = km + (size_t)(b1 * LDIM + tid) * NFEAT + h * DH;
    float s[8] = {0, 0, 0, 0, 0, 0, 0, 0};
#pragma unroll
    for (int i4 = 0; i4 < DH / 4; ++i4) {
      const float4 kmv = *(const float4*)(kmrow + i4 * 4);
#pragma unroll
      for (int b2 = 0; b2 < 8; ++b2) {
        const float4 qk4 = *(const float4*)(qk_s + b2 * DH + i4 * 4);
        s[b2] += kmv.x * qk4.x + kmv.y * qk4.y + kmv.z * qk4.z + kmv.w * qk4.w;
      }
    }
#pragma unroll
    for (int b2 = 0; b2 < 8; ++b2) sw[b2 * LDIM + tid] = s[b2] * 0.125f;
  }
  __syncthreads();
  {
    const int g = tid >> 4;
    const int r = tid & 15;
    float m = -1e30f;
#pragma unroll
    for (int k = 0; k < 8; ++k) m = fmaxf(m, sw[g * LDIM + r + k * 16]);
#pragma unroll
    for (int s = 1; s < 16; s <<= 1) m = fmaxf(m, __shfl_xor(m, s, 64));
    float ssum = 0.f;
#pragma unroll
    for (int k = 0; k < 8; ++k) ssum += expf(sw[g * LDIM + r + k * 16] - m);
#pragma unroll
    for (int s = 1; s < 16; s <<= 1) ssum += __shfl_xor(ssum, s, 64);
    if (r == 0) { mred[g] = m; ired[g] = 1.f / ssum; }
  }
  __syncthreads();
  {
    float* abase = attn + ((size_t)(b1 * HNUM + h) * BDIM) * LDIM + tid;
#pragma unroll
    for (int b2 = 0; b2 < 8; ++b2)
      abase[b2 * LDIM] = expf(sw[b2 * LDIM + tid] - mred[b2]) * ired[b2];
  }
}

// ---------------------------------------------------------------------------
// Kernel 3: pool (R3/R6-proven body, verbatim).
// ---------------------------------------------------------------------------
#define HSTRIDE 1032
__global__ __launch_bounds__(64) void pool_kernel(const float* __restrict__ kv,
                                                  const float* __restrict__ attn,
                                                  unsigned short* __restrict__ pooled) {
  __shared__ float wlds[4 * HSTRIDE];
  const int b1 = blockIdx.x;
  const int t = blockIdx.y;
  const int ftile = blockIdx.z;
  const int tid = threadIdx.x;
  {
#pragma unroll
    for (int hg = 0; hg < 4; ++hg) {
      const float* src = attn + ((size_t)(b1 * HNUM + ftile * 4 + hg)) * (BDIM * LDIM);
#pragma unroll
      for (int j = 0; j < 4; ++j) {
        const int idx = (j * 64 + tid) * 4;
        *(float4*)(wlds + hg * HSTRIDE + idx) = *(const float4*)(src + idx);
      }
    }
  }
  __syncthreads();
  const int f = ftile * 256 + tid * 4;
  const int hh = tid >> 4;
  const float* kvbase = kv + ((size_t)b1 * LDIM) * (TDIM * NFEAT) + t * NFEAT + f;
  float4 acc[8];
#pragma unroll
  for (int b2 = 0; b2 < 8; ++b2) acc[b2] = make_float4(0.f, 0.f, 0.f, 0.f);
  const float* wbase = wlds + hh * HSTRIDE;
  for (int l0 = 0; l0 < LDIM; l0 += 8) {
    float4 v[8];
#pragma unroll
    for (int j = 0; j < 8; ++j)
      v[j] = *(const float4*)(kvbase + (size_t)(l0 + j) * (TDIM * NFEAT));
#pragma unroll
    for (int j = 0; j < 8; ++j) {
#pragma unroll
      for (int b2 = 0; b2 < 8; ++b2) {
        const float w = wbase[b2 * LDIM + l0 + j];
        acc[b2].x += w * v[j].x; acc[b2].y += w * v[j].y;
        acc[b2].z += w * v[j].z; acc[b2].w += w * v[j].w;
      }
    }
  }
  unsigned short* obase = pooled + ((size_t)(b1 * TDIM + t) * BDIM) * NFEAT + f;
#pragma unroll
  for (int b2 = 0; b2 < 8; ++b2) {
    ushort4 pk;
    pk.x = f2bf(acc[b2].x); pk.y = f2bf(acc[b2].y);
    pk.z = f2bf(acc[b2].z); pk.w = f2bf(acc[b2].w);
    *(ushort4*)(obase + b2 * NFEAT) = pk;
  }
}

// ---------------------------------------------------------------------------
// Kernel 4: bf16 MFMA GEMM (R3/R6-proven body, verbatim).
// ---------------------------------------------------------------------------
__global__ __launch_bounds__(256) void mfma_gemm(const unsigned short* __restrict__ A,
                                                 const unsigned short* __restrict__ W,
                                                 const float* __restrict__ beff,
                                                 float* __restrict__ out) {
  __shared__ unsigned short As[2][128 * 32];
  __shared__ unsigned short Bs[2][64 * 32];
  const int tid = threadIdx.x;
  const int w = tid >> 6, l = tid & 63;
  const int mBase = blockIdx.y * 128, nBase = blockIdx.x * 64;
  const int wr = w >> 1, wc = w & 1;

  int arow[2], acol[2];
#pragma unroll
  for (int j = 0; j < 2; ++j) {
    const int cid = j * 256 + tid;
    const int r = cid >> 2, c = cid & 3;
    arow[j] = r;
    acol[j] = (c ^ ((r >> 1) & 3)) * 8;
  }
  const int brow = tid >> 2;
  const int bcol = ((tid & 3) ^ ((brow >> 1) & 3)) * 8;

  const int rl = l & 15, ks = l >> 4;
  const int fsel = (ks ^ ((rl >> 1) & 3)) * 16;

  f32x4 acc[4][2] = {};

#pragma unroll
  for (int j = 0; j < 2; ++j)
    gload_lds16(A + (size_t)(mBase + arow[j]) * GK + acol[j],
                (char*)As[0] + (j * 256 + tid) * 16);
  gload_lds16(W + (size_t)(nBase + brow) * GK + bcol, (char*)Bs[0] + tid * 16);
  __syncthreads();

  int cur = 0;
  for (int t = 0; t < GK / 32; ++t) {
    if (t + 1 < GK / 32) {
      const int k0 = (t + 1) * 32;
#pragma unroll
      for (int j = 0; j < 2; ++j)
        gload_lds16(A + (size_t)(mBase + arow[j]) * GK + k0 + acol[j],
                    (char*)As[cur ^ 1] + (j * 256 + tid) * 16);
      gload_lds16(W + (size_t)(nBase + brow) * GK + k0 + bcol,
                  (char*)Bs[cur ^ 1] + tid * 16);
    }
    short8 a[4], b[2];
#pragma unroll
    for (int m = 0; m < 4; ++m)
      a[m] = *(const short8*)((const char*)As[cur] + (wr * 64 + m * 16 + rl) * 64 + fsel);
#pragma unroll
    for (int n = 0; n < 2; ++n)
      b[n] = *(const short8*)((const char*)Bs[cur] + (wc * 32 + n * 16 + rl) * 64 + fsel);
#pragma unroll
    for (int m = 0; m < 4; ++m)
#pragma unroll
      for (int n = 0; n < 2; ++n)
        acc[m][n] = __builtin_amdgcn_mfma_f32_16x16x32_bf16(a[m], b[n], acc[m][n], 0, 0, 0);
    __syncthreads();
    cur ^= 1;
  }

#pragma unroll
  for (int n = 0; n < 2; ++n) {
    const int col = nBase + wc * 32 + n * 16 + rl;
    const float bv = beff[col];
#pragma unroll
    for (int m = 0; m < 4; ++m) {
      const int row0 = mBase + wr * 64 + m * 16 + ks * 4;
#pragma unroll
      for (int j2 = 0; j2 < 4; ++j2)
        out[(size_t)(row0 + j2) * GN + col] = acc[m][n][j2] + bv;
    }
  }
}

extern "C" void kernel_launch(void* const* d_in, const int* in_sizes, int n_in,
                              void* d_out, int out_size, void* d_ws, size_t ws_size,
                              hipStream_t stream) {
  const float* q  = (const float*)d_in[0];
  const float* kv = (const float*)d_in[1];
  const float* Wq = (const float*)d_in[2];
  const float* bq = (const float*)d_in[3];
  const float* Wk = (const float*)d_in[4];
  // d_in[5] = bk: dropped (constant shift per softmax row -> no effect)
  const float* Wv = (const float*)d_in[6];
  const float* bv = (const float*)d_in[7];
  const float* Wo = (const float*)d_in[8];
  const float* bo = (const float*)d_in[9];
  float* out = (float*)d_out;

  char* ws = (char*)d_ws;
  float*          km     = (float*)ws;                                // 4 MB
  float*          attnW  = (float*)(ws + (4u << 20));                 // 512 KB
  float*          beff   = (float*)(ws + (4u << 20) + (512u << 10));  // 4 KB
  unsigned short* Weff   = (unsigned short*)(ws + (4u << 20) + (516u << 10));               // 2 MB
  unsigned short* pooled = (unsigned short*)(ws + (4u << 20) + (516u << 10) + (2u << 20));  // 8 MB

  mean_weff_kernel<<<BDIM * LDIM, 256, 0, stream>>>(kv, Wo, Wv, bv, bo, km, Weff, beff);
  // ---- MEASUREMENT PROBE: attn launched 9x (idempotent; WAW-serialized).
  // delta vs R6 = 8 * (attn_dur + dispatch_gap)  ->  gap = delta/8 - ~3us.
  for (int rep = 0; rep < 9; ++rep)
    attn_kernel<<<dim3(BDIM, HNUM), 128, 0, stream>>>(q, km, Wq, bq, Wk, attnW);
  pool_kernel<<<dim3(BDIM, TDIM, 4), 64, 0, stream>>>(kv, attnW, pooled);
  mfma_gemm<<<dim3(GN / 64, GM / 128), 256, 0, stream>>>(pooled, Weff, beff, out);
}

// Round 8
// 156.457 us; speedup vs baseline: 1.5818x; 1.5818x over previous
//
#include <hip/hip_runtime.h>
#include <hip/hip_bf16.h>

#define BDIM 8
#define LDIM 128
#define TDIM 64
#define NFEAT 1024
#define HNUM 16
#define DH 64

#define GM 4096  // rows of pooled = B*T*B
#define GN 1024
#define GK 1024

typedef __attribute__((ext_vector_type(8))) short short8;
typedef __attribute__((ext_vector_type(4))) float f32x4;

// round-to-nearest-even f32 -> bf16 bits
__device__ __forceinline__ unsigned short f2bf(float x) {
  union { float f; unsigned u; } v; v.f = x;
  unsigned r = v.u + 0x7fffu + ((v.u >> 16) & 1u);
  return (unsigned short)(r >> 16);
}

__device__ __forceinline__ void gload_lds16(const void* g, void* l) {
  __builtin_amdgcn_global_load_lds((const __attribute__((address_space(1))) void*)g,
                                   (__attribute__((address_space(3))) void*)l, 16, 0, 0);
}

// ---------------------------------------------------------------------------
// Kernel 1: per block bl=(b1,l):
//   A: km = mean_t kv[bl]            (registers -> LDS; never written to HBM)
//   B: kw[h][dd]   = sum_d Wk[dd][d] * km[h*64+d]        (Wk staged, pad 67)
//   C: wqkw[h][i]  = sum_dd Wq[dd][i] * kw[h][dd]        (i-coalesced Wq reads)
//      bqkw[h]     = sum_dd bq[dd] * kw[h][dd]
//   D: score[h,b2] = (bqkw[h] + sum_i q[b2][h*64+i]*wqkw[h][i]) * 0.125
//      (64-lane product + shfl_xor reduce; == old qk.km algebraically)
//   E: weff row f=bl (R6-proven body)
// bk dropped (softmax-invariant).  Scores layout: [b1][l][h][b2].
// ---------------------------------------------------------------------------
__global__ __launch_bounds__(256) void mean_score_weff_kernel(
    const float* __restrict__ kv, const float* __restrict__ q,
    const float* __restrict__ Wq, const float* __restrict__ bq,
    const float* __restrict__ Wk, const float* __restrict__ Wo,
    const float* __restrict__ Wv, const float* __restrict__ bv,
    const float* __restrict__ bo, float* __restrict__ scores,
    unsigned short* __restrict__ Weff, float* __restrict__ beff) {
  __shared__ float km_s[NFEAT];        // 4 KB
  __shared__ float Wk_s[DH * 67];      // 17.2 KB (pad 67 -> 2-way-free reads)
  __shared__ float kw_s[HNUM * DH];    // 4 KB
  __shared__ float wqkw_s[HNUM * 66];  // 4.1 KB (pad 66 -> conflict-free)
  __shared__ float bqkw_s[HNUM];
  __shared__ float worow[NFEAT];       // 4 KB (weff)
  __shared__ float red[256];           // 1 KB (weff)
  const int bl = blockIdx.x;  // b1*128 + l
  const int tid = threadIdx.x;

  // ---- A: mean over t of kv[bl, t, :] -> km_s ----
  {
    const float* src = kv + (size_t)bl * (TDIM * NFEAT) + tid * 4;
    float4 acc = make_float4(0.f, 0.f, 0.f, 0.f);
    for (int t0 = 0; t0 < TDIM; t0 += 8) {
      float4 v[8];
#pragma unroll
      for (int jj = 0; jj < 8; ++jj)
        v[jj] = *(const float4*)(src + (t0 + jj) * NFEAT);
#pragma unroll
      for (int jj = 0; jj < 8; ++jj) {
        acc.x += v[jj].x; acc.y += v[jj].y; acc.z += v[jj].z; acc.w += v[jj].w;
      }
    }
    const float s = 1.f / TDIM;
    *(float4*)(km_s + tid * 4) = make_float4(acc.x * s, acc.y * s, acc.z * s, acc.w * s);
  }
  // stage Wk into padded LDS (independent of A; same barrier covers both)
#pragma unroll
  for (int rep = 0; rep < 4; ++rep) {
    const int e4 = rep * 256 + tid;     // 1024 float4s
    const int row = e4 >> 4, c4 = e4 & 15;
    const float4 v = *(const float4*)(Wk + row * DH + c4 * 4);
    float* dst = Wk_s + row * 67 + c4 * 4;
    dst[0] = v.x; dst[1] = v.y; dst[2] = v.z; dst[3] = v.w;
  }
  __syncthreads();
  // ---- B: kw ----
#pragma unroll
  for (int rep = 0; rep < 4; ++rep) {
    const int e = rep * 256 + tid;
    const int h = e >> 6, dd = e & 63;
    float acc = 0.f;
#pragma unroll 4
    for (int d = 0; d < DH; ++d) acc += Wk_s[dd * 67 + d] * km_s[h * 64 + d];
    kw_s[h * 64 + dd] = acc;
  }
  __syncthreads();
  // ---- C: wqkw + bqkw ----
#pragma unroll
  for (int rep = 0; rep < 4; ++rep) {
    const int e = rep * 256 + tid;
    const int h = e >> 6, i = e & 63;
    float acc = 0.f;
#pragma unroll 4
    for (int dd = 0; dd < DH; ++dd) acc += Wq[dd * DH + i] * kw_s[h * 64 + dd];
    wqkw_s[h * 66 + i] = acc;
  }
  if (tid < HNUM) {
    float acc = 0.f;
#pragma unroll 4
    for (int dd = 0; dd < DH; ++dd) acc += bq[dd] * kw_s[tid * 64 + dd];
    bqkw_s[tid] = acc;
  }
  __syncthreads();
  // ---- D: scores via 64-lane reduce (wave w handles entries w*32..w*32+31) ----
  {
    const int w = tid >> 6, lane = tid & 63;
    for (int k = 0; k < 32; ++k) {
      const int e = w * 32 + k;       // e = h*8 + b2
      const int h = e >> 3, b2 = e & 7;
      float p = q[b2 * NFEAT + h * DH + lane] * wqkw_s[h * 66 + lane];
#pragma unroll
      for (int s = 1; s < 64; s <<= 1) p += __shfl_xor(p, s, 64);
      if (lane == 0) scores[(size_t)bl * 128 + e] = (p + bqkw_s[h]) * 0.125f;
    }
  }
  // ---- E: weff row f = bl (R6-proven) ----
  {
    const int f = bl;
    *(float4*)(worow + tid * 4) = *(const float4*)(Wo + (size_t)f * NFEAT + tid * 4);
    __syncthreads();
    const int g0 = tid * 4;
    const int hbase = (g0 >> 6) << 6;
    const int i0 = g0 & 63;
    float a0 = 0, a1 = 0, a2 = 0, a3 = 0;
#pragma unroll 4
    for (int d = 0; d < DH; ++d) {
      const float wod = worow[hbase + d];
      const float4 wv4 = *(const float4*)(Wv + d * DH + i0);
      a0 += wod * wv4.x; a1 += wod * wv4.y; a2 += wod * wv4.z; a3 += wod * wv4.w;
    }
    ushort4 pk;
    pk.x = f2bf(a0); pk.y = f2bf(a1); pk.z = f2bf(a2); pk.w = f2bf(a3);
    *(ushort4*)(Weff + (size_t)f * NFEAT + g0) = pk;
    red[tid] = worow[g0 + 0] * bv[i0 + 0] + worow[g0 + 1] * bv[i0 + 1] +
               worow[g0 + 2] * bv[i0 + 2] + worow[g0 + 3] * bv[i0 + 3];
    __syncthreads();
    for (int sft = 128; sft > 0; sft >>= 1) {
      if (tid < sft) red[tid] += red[tid + sft];
      __syncthreads();
    }
    if (tid == 0) beff[f] = bo[f] + red[0];
  }
}

// ---------------------------------------------------------------------------
// Kernel 2: pool with softmax prologue.
// Block (b1,t,ftile), 64 threads = 1 wave.
// pass1: per (hb,half) row-stats over 64 l (coalesced L2-hot score reads),
//        shfl_xor(32) combine -> mrow/irow.
// pass2: w = exp(s-m)*inv into wldsT[l][hb] (pad 36): conflict-free writes,
//        4-distinct-bank broadcast reads in main loop.
// Main loop: R6-proven kv streaming body (8-deep float4 batches).
// ---------------------------------------------------------------------------
__global__ __launch_bounds__(64) void pool_kernel(
    const float* __restrict__ kv, const float* __restrict__ scores,
    unsigned short* __restrict__ pooled) {
  __shared__ float wldsT[LDIM * 36];   // 18 KB
  __shared__ float mrow[32], irow[32];
  const int b1 = blockIdx.x;
  const int t = blockIdx.y;
  const int ftile = blockIdx.z;
  const int tid = threadIdx.x;
  const float* sc = scores + (size_t)b1 * (LDIM * 128) + ftile * 32;  // + l*128 + hb
  // pass1: row max & sum
  {
    const int hb = tid & 31, half = tid >> 5;
    const float* scp = sc + (size_t)(half * 64) * 128 + hb;
    float m = -1e30f;
    for (int j = 0; j < 64; ++j) m = fmaxf(m, scp[j * 128]);
    m = fmaxf(m, __shfl_xor(m, 32, 64));
    float ssum = 0.f;
    for (int j = 0; j < 64; ++j) ssum += expf(scp[j * 128] - m);
    ssum += __shfl_xor(ssum, 32, 64);
    if (half == 0) { mrow[hb] = m; irow[hb] = 1.f / ssum; }
  }
  __syncthreads();
  // pass2: weights into transposed padded LDS
  for (int rep = 0; rep < 64; ++rep) {
    const int e = rep * 64 + tid;
    const int hb = e & 31, l = e >> 5;
    wldsT[l * 36 + hb] = expf(sc[(size_t)l * 128 + hb] - mrow[hb]) * irow[hb];
  }
  __syncthreads();
  // main loop (R6 body; new weight addressing)
  const int f = ftile * 256 + tid * 4;
  const int hh = tid >> 4;  // local head 0..3
  const float* kvbase = kv + ((size_t)b1 * LDIM) * (TDIM * NFEAT) + t * NFEAT + f;
  float4 acc[8];
#pragma unroll
  for (int b2 = 0; b2 < 8; ++b2) acc[b2] = make_float4(0.f, 0.f, 0.f, 0.f);
  for (int l0 = 0; l0 < LDIM; l0 += 8) {
    float4 v[8];
#pragma unroll
    for (int j = 0; j < 8; ++j)
      v[j] = *(const float4*)(kvbase + (size_t)(l0 + j) * (TDIM * NFEAT));
#pragma unroll
    for (int j = 0; j < 8; ++j) {
      const float* wrow = wldsT + (l0 + j) * 36 + hh * 8;
#pragma unroll
      for (int b2 = 0; b2 < 8; ++b2) {
        const float w = wrow[b2];
        acc[b2].x += w * v[j].x; acc[b2].y += w * v[j].y;
        acc[b2].z += w * v[j].z; acc[b2].w += w * v[j].w;
      }
    }
  }
  unsigned short* obase = pooled + ((size_t)(b1 * TDIM + t) * BDIM) * NFEAT + f;
#pragma unroll
  for (int b2 = 0; b2 < 8; ++b2) {
    ushort4 pk;
    pk.x = f2bf(acc[b2].x); pk.y = f2bf(acc[b2].y);
    pk.z = f2bf(acc[b2].z); pk.w = f2bf(acc[b2].w);
    *(ushort4*)(obase + b2 * NFEAT) = pk;
  }
}

// ---------------------------------------------------------------------------
// Kernel 3: bf16 MFMA GEMM (R3/R6-proven body, verbatim).
// ---------------------------------------------------------------------------
__global__ __launch_bounds__(256) void mfma_gemm(const unsigned short* __restrict__ A,
                                                 const unsigned short* __restrict__ W,
                                                 const float* __restrict__ beff,
                                                 float* __restrict__ out) {
  __shared__ unsigned short As[2][128 * 32];
  __shared__ unsigned short Bs[2][64 * 32];
  const int tid = threadIdx.x;
  const int w = tid >> 6, l = tid & 63;
  const int mBase = blockIdx.y * 128, nBase = blockIdx.x * 64;
  const int wr = w >> 1, wc = w & 1;

  int arow[2], acol[2];
#pragma unroll
  for (int j = 0; j < 2; ++j) {
    const int cid = j * 256 + tid;
    const int r = cid >> 2, c = cid & 3;
    arow[j] = r;
    acol[j] = (c ^ ((r >> 1) & 3)) * 8;
  }
  const int brow = tid >> 2;
  const int bcol = ((tid & 3) ^ ((brow >> 1) & 3)) * 8;

  const int rl = l & 15, ks = l >> 4;
  const int fsel = (ks ^ ((rl >> 1) & 3)) * 16;

  f32x4 acc[4][2] = {};

#pragma unroll
  for (int j = 0; j < 2; ++j)
    gload_lds16(A + (size_t)(mBase + arow[j]) * GK + acol[j],
                (char*)As[0] + (j * 256 + tid) * 16);
  gload_lds16(W + (size_t)(nBase + brow) * GK + bcol, (char*)Bs[0] + tid * 16);
  __syncthreads();

  int cur = 0;
  for (int t = 0; t < GK / 32; ++t) {
    if (t + 1 < GK / 32) {
      const int k0 = (t + 1) * 32;
#pragma unroll
      for (int j = 0; j < 2; ++j)
        gload_lds16(A + (size_t)(mBase + arow[j]) * GK + k0 + acol[j],
                    (char*)As[cur ^ 1] + (j * 256 + tid) * 16);
      gload_lds16(W + (size_t)(nBase + brow) * GK + k0 + bcol,
                  (char*)Bs[cur ^ 1] + tid * 16);
    }
    short8 a[4], b[2];
#pragma unroll
    for (int m = 0; m < 4; ++m)
      a[m] = *(const short8*)((const char*)As[cur] + (wr * 64 + m * 16 + rl) * 64 + fsel);
#pragma unroll
    for (int n = 0; n < 2; ++n)
      b[n] = *(const short8*)((const char*)Bs[cur] + (wc * 32 + n * 16 + rl) * 64 + fsel);
#pragma unroll
    for (int m = 0; m < 4; ++m)
#pragma unroll
      for (int n = 0; n < 2; ++n)
        acc[m][n] = __builtin_amdgcn_mfma_f32_16x16x32_bf16(a[m], b[n], acc[m][n], 0, 0, 0);
    __syncthreads();
    cur ^= 1;
  }

#pragma unroll
  for (int n = 0; n < 2; ++n) {
    const int col = nBase + wc * 32 + n * 16 + rl;
    const float bv = beff[col];
#pragma unroll
    for (int m = 0; m < 4; ++m) {
      const int row0 = mBase + wr * 64 + m * 16 + ks * 4;
#pragma unroll
      for (int j2 = 0; j2 < 4; ++j2)
        out[(size_t)(row0 + j2) * GN + col] = acc[m][n][j2] + bv;
    }
  }
}

extern "C" void kernel_launch(void* const* d_in, const int* in_sizes, int n_in,
                              void* d_out, int out_size, void* d_ws, size_t ws_size,
                              hipStream_t stream) {
  const float* q  = (const float*)d_in[0];
  const float* kv = (const float*)d_in[1];
  const float* Wq = (const float*)d_in[2];
  const float* bq = (const float*)d_in[3];
  const float* Wk = (const float*)d_in[4];
  // d_in[5] = bk: dropped (constant shift per softmax row -> no effect)
  const float* Wv = (const float*)d_in[6];
  const float* bv = (const float*)d_in[7];
  const float* Wo = (const float*)d_in[8];
  const float* bo = (const float*)d_in[9];
  float* out = (float*)d_out;

  char* ws = (char*)d_ws;
  float*          scores = (float*)ws;                      // 512 KB
  float*          beff   = (float*)(ws + (1u << 20));       // 4 KB
  unsigned short* Weff   = (unsigned short*)(ws + (1u << 20) + (4u << 10));  // 2 MB
  unsigned short* pooled = (unsigned short*)(ws + (4u << 20));               // 8 MB

  mean_score_weff_kernel<<<BDIM * LDIM, 256, 0, stream>>>(
      kv, q, Wq, bq, Wk, Wo, Wv, bv, bo, scores, Weff, beff);
  pool_kernel<<<dim3(BDIM, TDIM, 4), 64, 0, stream>>>(kv, scores, pooled);
  mfma_gemm<<<dim3(GN / 64, GM / 128), 256, 0, stream>>>(pooled, Weff, beff, out);
}

// Round 9
// 138.718 us; speedup vs baseline: 1.7841x; 1.1279x over previous
//
#include <hip/hip_runtime.h>
#include <hip/hip_bf16.h>

#define BDIM 8
#define LDIM 128
#define TDIM 64
#define NFEAT 1024
#define HNUM 16
#define DH 64

#define GM 4096  // rows of pooled = B*T*B
#define GN 1024
#define GK 1024

typedef __attribute__((ext_vector_type(8))) short short8;
typedef __attribute__((ext_vector_type(4))) float f32x4;

// round-to-nearest-even f32 -> bf16 bits
__device__ __forceinline__ unsigned short f2bf(float x) {
  union { float f; unsigned u; } v; v.f = x;
  unsigned r = v.u + 0x7fffu + ((v.u >> 16) & 1u);
  return (unsigned short)(r >> 16);
}

__device__ __forceinline__ void gload_lds16(const void* g, void* l) {
  __builtin_amdgcn_global_load_lds((const __attribute__((address_space(1))) void*)g,
                                   (__attribute__((address_space(3))) void*)l, 16, 0, 0);
}

// ---------------------------------------------------------------------------
// Kernel 1: per block bl=(b1,l):
//   A: km = mean_t kv[bl]                      (LDS only; never hits HBM)
//   B: kw[h][dd]  = sum_d Wk[dd][d]*km[h*64+d]   (Wk staged, pad 67)
//   C: wqkw[h][i] = sum_dd Wq[dd][i]*kw[h][dd]; bqkw[h] = sum_dd bq[dd]*kw[h][dd]
//   D: (FIXED vs R8) thread e<128 computes ONE score directly:
//        s[h,b2] = (bqkw[h] + sum_i q[b2][h*64+i]*wqkw[h][i]) * 0.125
//      64 FMA + 16 float4 L2-hot q-loads, NO cross-lane ops.
//   E: weff row f=bl (R6-proven body)
// Scores layout (FIXED vs R8): [b1][h][b2][l]  (contiguous in l).
// ---------------------------------------------------------------------------
__global__ __launch_bounds__(256) void mean_score_weff_kernel(
    const float* __restrict__ kv, const float* __restrict__ q,
    const float* __restrict__ Wq, const float* __restrict__ bq,
    const float* __restrict__ Wk, const float* __restrict__ Wo,
    const float* __restrict__ Wv, const float* __restrict__ bv,
    const float* __restrict__ bo, float* __restrict__ scores,
    unsigned short* __restrict__ Weff, float* __restrict__ beff) {
  __shared__ float km_s[NFEAT];        // 4 KB
  __shared__ float Wk_s[DH * 67];      // 17.2 KB (pad 67 -> 2-way-free reads)
  __shared__ float kw_s[HNUM * DH];    // 4 KB
  __shared__ float wqkw_s[HNUM * 66];  // 4.1 KB (pad 66)
  __shared__ float bqkw_s[HNUM];
  __shared__ float worow[NFEAT];       // 4 KB (weff)
  __shared__ float red[256];           // 1 KB (weff)
  const int bl = blockIdx.x;  // b1*128 + l
  const int tid = threadIdx.x;
  const int b1 = bl >> 7, l = bl & 127;

  // ---- A: mean over t of kv[bl, t, :] -> km_s ----
  {
    const float* src = kv + (size_t)bl * (TDIM * NFEAT) + tid * 4;
    float4 acc = make_float4(0.f, 0.f, 0.f, 0.f);
    for (int t0 = 0; t0 < TDIM; t0 += 8) {
      float4 v[8];
#pragma unroll
      for (int jj = 0; jj < 8; ++jj)
        v[jj] = *(const float4*)(src + (t0 + jj) * NFEAT);
#pragma unroll
      for (int jj = 0; jj < 8; ++jj) {
        acc.x += v[jj].x; acc.y += v[jj].y; acc.z += v[jj].z; acc.w += v[jj].w;
      }
    }
    const float s = 1.f / TDIM;
    *(float4*)(km_s + tid * 4) = make_float4(acc.x * s, acc.y * s, acc.z * s, acc.w * s);
  }
  // stage Wk into padded LDS (same barrier covers A and this)
#pragma unroll
  for (int rep = 0; rep < 4; ++rep) {
    const int e4 = rep * 256 + tid;     // 1024 float4s
    const int row = e4 >> 4, c4 = e4 & 15;
    const float4 v = *(const float4*)(Wk + row * DH + c4 * 4);
    float* dst = Wk_s + row * 67 + c4 * 4;
    dst[0] = v.x; dst[1] = v.y; dst[2] = v.z; dst[3] = v.w;
  }
  __syncthreads();
  // ---- B: kw ----
#pragma unroll
  for (int rep = 0; rep < 4; ++rep) {
    const int e = rep * 256 + tid;
    const int h = e >> 6, dd = e & 63;
    float acc = 0.f;
#pragma unroll 4
    for (int d = 0; d < DH; ++d) acc += Wk_s[dd * 67 + d] * km_s[h * 64 + d];
    kw_s[h * 64 + dd] = acc;
  }
  __syncthreads();
  // ---- C: wqkw + bqkw ----
#pragma unroll
  for (int rep = 0; rep < 4; ++rep) {
    const int e = rep * 256 + tid;
    const int h = e >> 6, i = e & 63;
    float acc = 0.f;
#pragma unroll 4
    for (int dd = 0; dd < DH; ++dd) acc += Wq[dd * DH + i] * kw_s[h * 64 + dd];
    wqkw_s[h * 66 + i] = acc;
  }
  if (tid < HNUM) {
    float acc = 0.f;
#pragma unroll 4
    for (int dd = 0; dd < DH; ++dd) acc += bq[dd] * kw_s[tid * 64 + dd];
    bqkw_s[tid] = acc;
  }
  __syncthreads();
  // ---- D: direct per-thread score dots (no shuffles) ----
  if (tid < 128) {
    const int h = tid >> 3, b2 = tid & 7;
    const float* qrow = q + b2 * NFEAT + h * DH;
    const float* wrow = wqkw_s + h * 66;
    float acc = 0.f;
#pragma unroll
    for (int i4 = 0; i4 < 16; ++i4) {
      const float4 qv = *(const float4*)(qrow + i4 * 4);
      acc += qv.x * wrow[i4 * 4 + 0] + qv.y * wrow[i4 * 4 + 1] +
             qv.z * wrow[i4 * 4 + 2] + qv.w * wrow[i4 * 4 + 3];
    }
    scores[(((size_t)b1 * HNUM + h) * BDIM + b2) * LDIM + l] =
        (acc + bqkw_s[h]) * 0.125f;
  }
  // ---- E: weff row f = bl (R6-proven) ----
  {
    const int f = bl;
    *(float4*)(worow + tid * 4) = *(const float4*)(Wo + (size_t)f * NFEAT + tid * 4);
    __syncthreads();
    const int g0 = tid * 4;
    const int hbase = (g0 >> 6) << 6;
    const int i0 = g0 & 63;
    float a0 = 0, a1 = 0, a2 = 0, a3 = 0;
#pragma unroll 4
    for (int d = 0; d < DH; ++d) {
      const float wod = worow[hbase + d];
      const float4 wv4 = *(const float4*)(Wv + d * DH + i0);
      a0 += wod * wv4.x; a1 += wod * wv4.y; a2 += wod * wv4.z; a3 += wod * wv4.w;
    }
    ushort4 pk;
    pk.x = f2bf(a0); pk.y = f2bf(a1); pk.z = f2bf(a2); pk.w = f2bf(a3);
    *(ushort4*)(Weff + (size_t)f * NFEAT + g0) = pk;
    red[tid] = worow[g0 + 0] * bv[i0 + 0] + worow[g0 + 1] * bv[i0 + 1] +
               worow[g0 + 2] * bv[i0 + 2] + worow[g0 + 3] * bv[i0 + 3];
    __syncthreads();
    for (int sft = 128; sft > 0; sft >>= 1) {
      if (tid < sft) red[tid] += red[tid + sft];
      __syncthreads();
    }
    if (tid == 0) beff[f] = bo[f] + red[0];
  }
}

// ---------------------------------------------------------------------------
// Kernel 2: pool with softmax prologue (FIXED vs R8).
// Block (b1,t,ftile), 64 threads. Thread (row=hloc*8+b2, half) reads its
// 64 CONTIGUOUS scores (16 float4, coalesced, L2-hot), one shfl_xor(32)
// combine for max/sum, weights into R6's wlds[4][1032] layout.
// Main loop: R6-proven kv streaming body, verbatim.
// ---------------------------------------------------------------------------
#define HSTRIDE 1032
__global__ __launch_bounds__(64) void pool_kernel(
    const float* __restrict__ kv, const float* __restrict__ scores,
    unsigned short* __restrict__ pooled) {
  __shared__ float wlds[4 * HSTRIDE];   // 16.5 KB
  const int b1 = blockIdx.x;
  const int t = blockIdx.y;
  const int ftile = blockIdx.z;
  const int tid = threadIdx.x;
  // ---- softmax prologue ----
  {
    const int row = tid & 31;           // hloc*8 + b2
    const int half = tid >> 5;
    const int hloc = row >> 3, b2 = row & 7;
    const float* srow = scores +
        (((size_t)b1 * HNUM + ftile * 4 + hloc) * BDIM + b2) * LDIM + half * 64;
    float4 sv[16];
#pragma unroll
    for (int j = 0; j < 16; ++j) sv[j] = *(const float4*)(srow + j * 4);
    float m = -1e30f;
#pragma unroll
    for (int j = 0; j < 16; ++j)
      m = fmaxf(m, fmaxf(fmaxf(sv[j].x, sv[j].y), fmaxf(sv[j].z, sv[j].w)));
    m = fmaxf(m, __shfl_xor(m, 32, 64));
    float ssum = 0.f;
#pragma unroll
    for (int j = 0; j < 16; ++j) {
      sv[j].x = expf(sv[j].x - m); sv[j].y = expf(sv[j].y - m);
      sv[j].z = expf(sv[j].z - m); sv[j].w = expf(sv[j].w - m);
      ssum += sv[j].x + sv[j].y + sv[j].z + sv[j].w;
    }
    ssum += __shfl_xor(ssum, 32, 64);
    const float inv = 1.f / ssum;
    float* wdst = wlds + hloc * HSTRIDE + b2 * LDIM + half * 64;
#pragma unroll
    for (int j = 0; j < 16; ++j) {
      float4 w4 = make_float4(sv[j].x * inv, sv[j].y * inv, sv[j].z * inv, sv[j].w * inv);
      *(float4*)(wdst + j * 4) = w4;
    }
  }
  __syncthreads();
  // ---- main loop (R6 body, verbatim) ----
  const int f = ftile * 256 + tid * 4;
  const int hh = tid >> 4;
  const float* kvbase = kv + ((size_t)b1 * LDIM) * (TDIM * NFEAT) + t * NFEAT + f;
  float4 acc[8];
#pragma unroll
  for (int b2 = 0; b2 < 8; ++b2) acc[b2] = make_float4(0.f, 0.f, 0.f, 0.f);
  const float* wbase = wlds + hh * HSTRIDE;
  for (int l0 = 0; l0 < LDIM; l0 += 8) {
    float4 v[8];
#pragma unroll
    for (int j = 0; j < 8; ++j)
      v[j] = *(const float4*)(kvbase + (size_t)(l0 + j) * (TDIM * NFEAT));
#pragma unroll
    for (int j = 0; j < 8; ++j) {
#pragma unroll
      for (int b2 = 0; b2 < 8; ++b2) {
        const float w = wbase[b2 * LDIM + l0 + j];
        acc[b2].x += w * v[j].x; acc[b2].y += w * v[j].y;
        acc[b2].z += w * v[j].z; acc[b2].w += w * v[j].w;
      }
    }
  }
  unsigned short* obase = pooled + ((size_t)(b1 * TDIM + t) * BDIM) * NFEAT + f;
#pragma unroll
  for (int b2 = 0; b2 < 8; ++b2) {
    ushort4 pk;
    pk.x = f2bf(acc[b2].x); pk.y = f2bf(acc[b2].y);
    pk.z = f2bf(acc[b2].z); pk.w = f2bf(acc[b2].w);
    *(ushort4*)(obase + b2 * NFEAT) = pk;
  }
}

// ---------------------------------------------------------------------------
// Kernel 3: bf16 MFMA GEMM (R3/R6-proven body, verbatim).
// ---------------------------------------------------------------------------
__global__ __launch_bounds__(256) void mfma_gemm(const unsigned short* __restrict__ A,
                                                 const unsigned short* __restrict__ W,
                                                 const float* __restrict__ beff,
                                                 float* __restrict__ out) {
  __shared__ unsigned short As[2][128 * 32];
  __shared__ unsigned short Bs[2][64 * 32];
  const int tid = threadIdx.x;
  const int w = tid >> 6, l = tid & 63;
  const int mBase = blockIdx.y * 128, nBase = blockIdx.x * 64;
  const int wr = w >> 1, wc = w & 1;

  int arow[2], acol[2];
#pragma unroll
  for (int j = 0; j < 2; ++j) {
    const int cid = j * 256 + tid;
    const int r = cid >> 2, c = cid & 3;
    arow[j] = r;
    acol[j] = (c ^ ((r >> 1) & 3)) * 8;
  }
  const int brow = tid >> 2;
  const int bcol = ((tid & 3) ^ ((brow >> 1) & 3)) * 8;

  const int rl = l & 15, ks = l >> 4;
  const int fsel = (ks ^ ((rl >> 1) & 3)) * 16;

  f32x4 acc[4][2] = {};

#pragma unroll
  for (int j = 0; j < 2; ++j)
    gload_lds16(A + (size_t)(mBase + arow[j]) * GK + acol[j],
                (char*)As[0] + (j * 256 + tid) * 16);
  gload_lds16(W + (size_t)(nBase + brow) * GK + bcol, (char*)Bs[0] + tid * 16);
  __syncthreads();

  int cur = 0;
  for (int t = 0; t < GK / 32; ++t) {
    if (t + 1 < GK / 32) {
      const int k0 = (t + 1) * 32;
#pragma unroll
      for (int j = 0; j < 2; ++j)
        gload_lds16(A + (size_t)(mBase + arow[j]) * GK + k0 + acol[j],
                    (char*)As[cur ^ 1] + (j * 256 + tid) * 16);
      gload_lds16(W + (size_t)(nBase + brow) * GK + k0 + bcol,
                  (char*)Bs[cur ^ 1] + tid * 16);
    }
    short8 a[4], b[2];
#pragma unroll
    for (int m = 0; m < 4; ++m)
      a[m] = *(const short8*)((const char*)As[cur] + (wr * 64 + m * 16 + rl) * 64 + fsel);
#pragma unroll
    for (int n = 0; n < 2; ++n)
      b[n] = *(const short8*)((const char*)Bs[cur] + (wc * 32 + n * 16 + rl) * 64 + fsel);
#pragma unroll
    for (int m = 0; m < 4; ++m)
#pragma unroll
      for (int n = 0; n < 2; ++n)
        acc[m][n] = __builtin_amdgcn_mfma_f32_16x16x32_bf16(a[m], b[n], acc[m][n], 0, 0, 0);
    __syncthreads();
    cur ^= 1;
  }

#pragma unroll
  for (int n = 0; n < 2; ++n) {
    const int col = nBase + wc * 32 + n * 16 + rl;
    const float bv = beff[col];
#pragma unroll
    for (int m = 0; m < 4; ++m) {
      const int row0 = mBase + wr * 64 + m * 16 + ks * 4;
#pragma unroll
      for (int j2 = 0; j2 < 4; ++j2)
        out[(size_t)(row0 + j2) * GN + col] = acc[m][n][j2] + bv;
    }
  }
}

extern "C" void kernel_launch(void* const* d_in, const int* in_sizes, int n_in,
                              void* d_out, int out_size, void* d_ws, size_t ws_size,
                              hipStream_t stream) {
  const float* q  = (const float*)d_in[0];
  const float* kv = (const float*)d_in[1];
  const float* Wq = (const float*)d_in[2];
  const float* bq = (const float*)d_in[3];
  const float* Wk = (const float*)d_in[4];
  // d_in[5] = bk: dropped (constant shift per softmax row -> no effect)
  const float* Wv = (const float*)d_in[6];
  const float* bv = (const float*)d_in[7];
  const float* Wo = (const float*)d_in[8];
  const float* bo = (const float*)d_in[9];
  float* out = (float*)d_out;

  char* ws = (char*)d_ws;
  float*          scores = (float*)ws;                      // 512 KB  [b1][h][b2][l]
  float*          beff   = (float*)(ws + (1u << 20));       // 4 KB
  unsigned short* Weff   = (unsigned short*)(ws + (1u << 20) + (4u << 10));  // 2 MB
  unsigned short* pooled = (unsigned short*)(ws + (4u << 20));               // 8 MB

  mean_score_weff_kernel<<<BDIM * LDIM, 256, 0, stream>>>(
      kv, q, Wq, bq, Wk, Wo, Wv, bv, bo, scores, Weff, beff);
  pool_kernel<<<dim3(BDIM, TDIM, 4), 64, 0, stream>>>(kv, scores, pooled);
  mfma_gemm<<<dim3(GN / 64, GM / 128), 256, 0, stream>>>(pooled, Weff, beff, out);
}